// Round 4
// baseline (43.588 us; speedup 1.0000x reference)
//
#include <hip/hip_runtime.h>

// Problem constants (from reference):
//   RAW_NODES = 10242, NEW_NODES = 4*10242-6 = 40962, B=8, C=128
//   x: (B, C, RAW) f32
//   out: (B, C, NOUT) f32 = concat( x[:,:,top//7],  mean-pairs of x[:,:,down//7] )
#define RAW    10242
#define LDSN   10240   // floats staged in LDS: 40960 B = 40 KiB exactly -> 4 blocks/CU
#define NOUT   40962
#define NPAIR  30720   // NOUT - RAW
#define BC     1024    // B * C
#define TPB    512

// R3 post-mortem: 41 KB LDS -> 3 blocks/CU -> 1024-block grid runs as
// 768 + 256-block tail wave (~20% idle). Trim LDS to exactly 40 KiB by
// keeping the last 2 row elements in registers: 4 blocks/CU, all 1024
// blocks co-resident in ONE grid wave, 32 waves/CU.
__device__ __forceinline__ float gat(const float* __restrict__ lds,
                                     float r0, float r1, unsigned s) {
    // s in [0, RAW). Branchless: clamped LDS read + 2 selects for the
    // two register-held tail elements.
    float v = lds[min(s, (unsigned)(LDSN - 1))];
    v = (s == (unsigned)LDSN)     ? r0 : v;
    v = (s == (unsigned)LDSN + 1) ? r1 : v;
    return v;
}

__global__ __launch_bounds__(TPB, 8) void upconv_layer_batch_average_kernel(
    const float* __restrict__ x,
    const int*   __restrict__ top,     // RAW entries, value in [0, 7*RAW)
    const int*   __restrict__ down,    // 2*NPAIR entries
    float*       __restrict__ out)
{
    __shared__ float ldsrow[LDSN];     // 40960 B exactly

    const int row = blockIdx.x;        // 0..BC-1  == (b*C + c)
    const float* __restrict__ xr   = x   + (size_t)row * RAW;
    float*       __restrict__ outr = out + (size_t)row * (size_t)NOUT;

    // --- Stage first 10240 floats of the row into LDS (float2; row base
    // is 8B-aligned). 5120 float2 = 10*512 exactly.
    const float2* __restrict__ xr2 = (const float2*)xr;
    float2* lds2 = (float2*)ldsrow;
    #pragma unroll
    for (int i = 0; i < 10; ++i) {
        int idx = i * TPB + threadIdx.x;
        lds2[idx] = xr2[idx];
    }
    // Tail elements live in registers (per-wave broadcast load, L1-hit).
    const float r0 = xr[LDSN];
    const float r1 = xr[LDSN + 1];
    __syncthreads();

    // --- Region 1: out[2p:2p+2] = { row[top[2p]/7], row[top[2p+1]/7] }
    const int2* __restrict__ top2 = (const int2*)top;
    float2* __restrict__ out2 = (float2*)outr;
    for (int p = threadIdx.x; p < RAW / 2; p += TPB) {
        int2 t = top2[p];
        float2 v;
        v.x = gat(ldsrow, r0, r1, (unsigned)t.x / 7u);
        v.y = gat(ldsrow, r0, r1, (unsigned)t.y / 7u);
        out2[p] = v;
    }

    // --- Region 2: two averaged outputs per thread-iter.
    // 15360 float2 = 30 * 512 exactly.
    const int4* __restrict__ downp4 = (const int4*)down;
    float2* __restrict__ outd2 = (float2*)(outr + RAW);
    #pragma unroll 2
    for (int m = threadIdx.x; m < NPAIR / 2; m += TPB) {
        int4 d = downp4[m];
        float2 v;
        v.x = 0.5f * (gat(ldsrow, r0, r1, (unsigned)d.x / 7u) +
                      gat(ldsrow, r0, r1, (unsigned)d.y / 7u));
        v.y = 0.5f * (gat(ldsrow, r0, r1, (unsigned)d.z / 7u) +
                      gat(ldsrow, r0, r1, (unsigned)d.w / 7u));
        outd2[m] = v;
    }
}

extern "C" void kernel_launch(void* const* d_in, const int* in_sizes, int n_in,
                              void* d_out, int out_size, void* d_ws, size_t ws_size,
                              hipStream_t stream) {
    const float* x    = (const float*)d_in[0];
    const int*   top  = (const int*)d_in[1];
    const int*   down = (const int*)d_in[2];
    float*       out  = (float*)d_out;

    upconv_layer_batch_average_kernel<<<dim3(BC), TPB, 0, stream>>>(x, top, down, out);
}

// Round 5
// 38.088 us; speedup vs baseline: 1.1444x; 1.1444x over previous
//
#include <hip/hip_runtime.h>

// Problem constants (from reference):
//   RAW_NODES = 10242, NEW_NODES = 4*10242-6 = 40962, B=8, C=128
//   x: (B, C, RAW) f32
//   out: (B, C, NOUT) f32 = concat( x[:,:,top//7],  mean-pairs of x[:,:,down//7] )
#define RAW    10242
#define LDSN   10240   // floats per row staged in LDS (40960 B)
#define NOUT   40962
#define NPAIR  30720   // NOUT - RAW
#define BC     1024    // B * C
#define TPB    512

// R4 post-mortem: branchless tail-select cost ~4.7us VALU == the whole
// regression; occupancy 3->4 blocks/CU gained ~0. R5 theory: the hidden
// cost is index-array re-reads (1024 blocks x 614 KB = 629 MB of L2->L1).
// Fix: 2 rows per block -- each index is loaded + divided ONCE and used
// for both rows' gathers. Grid = 512 = 2 blocks/CU exactly (zero tail).
// LDS = 2 x 40960 B; the 2 tail elements per row (s>=10240, ~0.02% of
// indices) go through a rarely-taken branch to global loads (L2-hot).
__global__ __launch_bounds__(TPB, 4) void upconv_layer_batch_average_kernel(
    const float* __restrict__ x,
    const int*   __restrict__ top,     // RAW entries, value in [0, 7*RAW)
    const int*   __restrict__ down,    // 2*NPAIR entries
    float*       __restrict__ out)
{
    __shared__ float lds[2][LDSN];     // 81920 B -> 2 blocks/CU (160 KiB exactly)

    const int r0 = blockIdx.x * 2;     // rows r0, r0+1
    const float* __restrict__ xr0 = x + (size_t)r0 * RAW;
    const float* __restrict__ xr1 = xr0 + RAW;
    float* __restrict__ o0 = out + (size_t)r0 * (size_t)NOUT;
    float* __restrict__ o1 = o0 + NOUT;

    // --- Stage first 10240 floats of each row (float2; bases 8B-aligned).
    // 5120 float2 per row = 10 iters of 512 threads.
    const float2* __restrict__ x02 = (const float2*)xr0;
    const float2* __restrict__ x12 = (const float2*)xr1;
    float2* l02 = (float2*)lds[0];
    float2* l12 = (float2*)lds[1];
    #pragma unroll
    for (int i = 0; i < 10; ++i) {
        int idx = i * TPB + threadIdx.x;
        l02[idx] = x02[idx];
        l12[idx] = x12[idx];
    }
    __syncthreads();

    // --- Region 1: 5121 int2 index-pairs cover all 10242 entries.
    const int2* __restrict__ top2 = (const int2*)top;
    float2* __restrict__ o0_2 = (float2*)o0;
    float2* __restrict__ o1_2 = (float2*)o1;
    for (int p = threadIdx.x; p < RAW / 2 + 1; p += TPB) {   // 5121
        int2 t = top2[p];
        unsigned s0 = (unsigned)t.x / 7u;
        unsigned s1 = (unsigned)t.y / 7u;
        unsigned mx = s0 > s1 ? s0 : s1;
        float2 a, b;
        if (__builtin_expect(mx >= (unsigned)LDSN, 0)) {
            // rare: tail elements live only in global (L2-hot after staging)
            a.x = xr0[s0]; a.y = xr0[s1];
            b.x = xr1[s0]; b.y = xr1[s1];
        } else {
            a.x = lds[0][s0]; a.y = lds[0][s1];
            b.x = lds[1][s0]; b.y = lds[1][s1];
        }
        o0_2[p] = a;
        o1_2[p] = b;
    }

    // --- Region 2: 15360 int4 loads (4 indices = 2 outputs) x 2 rows.
    // 15360 = 30 * 512 exactly.
    const int4* __restrict__ d4 = (const int4*)down;
    float2* __restrict__ od0 = (float2*)(o0 + RAW);
    float2* __restrict__ od1 = (float2*)(o1 + RAW);
    for (int m = threadIdx.x; m < NPAIR / 2; m += TPB) {
        int4 d = d4[m];
        unsigned s0 = (unsigned)d.x / 7u;
        unsigned s1 = (unsigned)d.y / 7u;
        unsigned s2 = (unsigned)d.z / 7u;
        unsigned s3 = (unsigned)d.w / 7u;
        unsigned m01 = s0 > s1 ? s0 : s1;
        unsigned m23 = s2 > s3 ? s2 : s3;
        unsigned mx  = m01 > m23 ? m01 : m23;
        float2 a, b;
        if (__builtin_expect(mx >= (unsigned)LDSN, 0)) {
            a.x = 0.5f * (xr0[s0] + xr0[s1]); a.y = 0.5f * (xr0[s2] + xr0[s3]);
            b.x = 0.5f * (xr1[s0] + xr1[s1]); b.y = 0.5f * (xr1[s2] + xr1[s3]);
        } else {
            a.x = 0.5f * (lds[0][s0] + lds[0][s1]); a.y = 0.5f * (lds[0][s2] + lds[0][s3]);
            b.x = 0.5f * (lds[1][s0] + lds[1][s1]); b.y = 0.5f * (lds[1][s2] + lds[1][s3]);
        }
        od0[m] = a;
        od1[m] = b;
    }
}

extern "C" void kernel_launch(void* const* d_in, const int* in_sizes, int n_in,
                              void* d_out, int out_size, void* d_ws, size_t ws_size,
                              hipStream_t stream) {
    const float* x    = (const float*)d_in[0];
    const int*   top  = (const int*)d_in[1];
    const int*   down = (const int*)d_in[2];
    float*       out  = (float*)d_out;

    upconv_layer_batch_average_kernel<<<dim3(BC / 2), TPB, 0, stream>>>(x, top, down, out);
}